// Round 4
// baseline (580.691 us; speedup 1.0000x reference)
//
#include <hip/hip_runtime.h>
#include <hip/hip_bf16.h>
#include <stdint.h>

#define NN 100000
#define NE 1600000
#define IND 512
#define HID 128
#define OUTD 64
#define BN_EPS 1e-5f
#define NBLK 391   // ceil(NN/256)

typedef __attribute__((ext_vector_type(8))) short short8v;
typedef __attribute__((ext_vector_type(4))) float f32x4;

// ---- fp32 -> bf16 (RNE) returning the bf16-as-fp32 value for residual ----
__device__ __forceinline__ ushort f2bf(float f, float& back) {
  uint u = __float_as_uint(f);
  uint r = u + 0x7FFFu + ((u >> 16) & 1u);
  ushort h = (ushort)(r >> 16);
  back = __uint_as_float(((uint)h) << 16);
  return h;
}
__device__ __forceinline__ ushort f2bf_n(float f) {
  uint u = __float_as_uint(f);
  uint r = u + 0x7FFFu + ((u >> 16) & 1u);
  return (ushort)(r >> 16);
}
__device__ __forceinline__ float bf2f(ushort h) {
  return __uint_as_float(((uint)h) << 16);
}

// ---------------- edge dtype probe -----------------------------------------
__global__ void k_detect(const int* __restrict__ e, int* __restrict__ flag) {
  __shared__ int nz;
  if (threadIdx.x == 0) nz = 0;
  __syncthreads();
  int v = e[2 * threadIdx.x + 1];
  if (v != 0) atomicAdd(&nz, 1);
  __syncthreads();
  if (threadIdx.x == 0) *flag = (nz == 0) ? 1 : 0;  // 1 => int64
}

__device__ __forceinline__ int edge_at(const int* e32, int f, int i) {
  if (f) return (int)((const long long*)e32)[i];
  return e32[i];
}

// ---------------- W1^T split prep: Wt[n][k] hi/lo bf16 ----------------------
__global__ void k_prepW(const float* __restrict__ W1, ushort* __restrict__ Wth,
                        ushort* __restrict__ Wtl) {
  int i = blockIdx.x * 256 + threadIdx.x;  // over 128*512
  if (i >= HID * IND) return;
  int n = i >> 9, k = i & 511;
  float w = W1[(size_t)k * HID + n];
  float back;
  ushort h = f2bf(w, back);
  Wth[i] = h;
  Wtl[i] = f2bf_n(w - back);
}

// ---------------- GEMM1 via split-bf16 MFMA: h1b = bf16(x @ W1) -------------
// BM=128, BN=128(=HID), BK=32, 16 K-steps. 4 waves (2x2), wave tile 64x64.
// 2-term: x_hi*(W_hi + W_lo); dropping x_lo*W_hi adds ~2^-9 relative error.
__global__ __launch_bounds__(256) void k_gemm1m(const float* __restrict__ x,
                                                const ushort* __restrict__ Wth,
                                                const ushort* __restrict__ Wtl,
                                                ushort* __restrict__ h1b) {
  __shared__ ushort sAh[128 * 40];
  __shared__ ushort sBh[128 * 40], sBl[128 * 40];
  const int tid = threadIdx.x;
  const int lane = tid & 63, wid = tid >> 6;
  const int wr = wid >> 1, wc = wid & 1;
  const int lrow = lane & 15, lkg = lane >> 4;
  const int row0 = blockIdx.x * 128;

  f32x4 acc[4][4];
#pragma unroll
  for (int m = 0; m < 4; ++m)
#pragma unroll
    for (int n = 0; n < 4; ++n) acc[m][n] = (f32x4){0.f, 0.f, 0.f, 0.f};

  float4 ra[4];
  uint4 rbh[2], rbl[2];

  // ---- load tile 0
#pragma unroll
  for (int i = 0; i < 4; ++i) {
    int flat = i * 256 + tid, r = flat >> 3, kq = flat & 7;
    int grow = row0 + r; if (grow > NN - 1) grow = NN - 1;
    ra[i] = *(const float4*)(x + (size_t)grow * IND + kq * 4);
  }
#pragma unroll
  for (int i = 0; i < 2; ++i) {
    int flat = i * 256 + tid, col = flat >> 2, kc = flat & 3;
    rbh[i] = *(const uint4*)(Wth + (size_t)col * IND + kc * 8);
    rbl[i] = *(const uint4*)(Wtl + (size_t)col * IND + kc * 8);
  }

  for (int s = 0; s < 16; ++s) {
    __syncthreads();  // prior step's LDS reads complete
    // ---- regs -> LDS (A hi only)
#pragma unroll
    for (int i = 0; i < 4; ++i) {
      int flat = i * 256 + tid, r = flat >> 3, kq = flat & 7;
      ushort4 hi;
      hi.x = f2bf_n(ra[i].x);
      hi.y = f2bf_n(ra[i].y);
      hi.z = f2bf_n(ra[i].z);
      hi.w = f2bf_n(ra[i].w);
      *(ushort4*)&sAh[r * 40 + kq * 4] = hi;
    }
#pragma unroll
    for (int i = 0; i < 2; ++i) {
      int flat = i * 256 + tid, col = flat >> 2, kc = flat & 3;
      *(uint4*)&sBh[col * 40 + kc * 8] = rbh[i];
      *(uint4*)&sBl[col * 40 + kc * 8] = rbl[i];
    }
    // ---- issue next tile's global loads (overlap with MFMA below)
    if (s < 15) {
      int kt = (s + 1) * 32;
#pragma unroll
      for (int i = 0; i < 4; ++i) {
        int flat = i * 256 + tid, r = flat >> 3, kq = flat & 7;
        int grow = row0 + r; if (grow > NN - 1) grow = NN - 1;
        ra[i] = *(const float4*)(x + (size_t)grow * IND + kt + kq * 4);
      }
#pragma unroll
      for (int i = 0; i < 2; ++i) {
        int flat = i * 256 + tid, col = flat >> 2, kc = flat & 3;
        rbh[i] = *(const uint4*)(Wth + (size_t)col * IND + kt + kc * 8);
        rbl[i] = *(const uint4*)(Wtl + (size_t)col * IND + kt + kc * 8);
      }
    }
    __syncthreads();  // LDS writes visible
    // ---- fragments + 32 MFMA
    short8v ah[4], bh[4], bl[4];
#pragma unroll
    for (int m = 0; m < 4; ++m) {
      int r = wr * 64 + m * 16 + lrow;
      ah[m] = *(const short8v*)&sAh[r * 40 + lkg * 8];
    }
#pragma unroll
    for (int n = 0; n < 4; ++n) {
      int c = wc * 64 + n * 16 + lrow;
      bh[n] = *(const short8v*)&sBh[c * 40 + lkg * 8];
      bl[n] = *(const short8v*)&sBl[c * 40 + lkg * 8];
    }
#pragma unroll
    for (int m = 0; m < 4; ++m)
#pragma unroll
      for (int n = 0; n < 4; ++n) {
        acc[m][n] = __builtin_amdgcn_mfma_f32_16x16x32_bf16(ah[m], bh[n], acc[m][n], 0, 0, 0);
        acc[m][n] = __builtin_amdgcn_mfma_f32_16x16x32_bf16(ah[m], bl[n], acc[m][n], 0, 0, 0);
      }
  }

  // ---- epilogue: store bf16 h1
#pragma unroll
  for (int m = 0; m < 4; ++m) {
    int orow0 = row0 + wr * 64 + m * 16 + (lane >> 4) * 4;
#pragma unroll
    for (int i = 0; i < 4; ++i) {
      int grow = orow0 + i;
      if (grow < NN) {
#pragma unroll
        for (int n = 0; n < 4; ++n) {
          h1b[(size_t)grow * HID + wc * 64 + n * 16 + (lane & 15)] = f2bf_n(acc[m][n][i]);
        }
      }
    }
  }
}

// ---------------- CSR build ------------------------------------------------
__global__ void k_count(const int* __restrict__ edges, const int* __restrict__ flag,
                        int* __restrict__ cnt) {
  int e = blockIdx.x * 256 + threadIdx.x;
  if (e < NE) {
    int f = *flag;
    atomicAdd(&cnt[edge_at(edges, f, NE + e)], 1);
  }
}

__global__ void k_s1(const int* __restrict__ cnt, int* __restrict__ bsum) {
  __shared__ int s[256];
  int tid = threadIdx.x;
  int i = blockIdx.x * 256 + tid;
  s[tid] = (i < NN) ? cnt[i] : 0;
  __syncthreads();
  for (int off = 128; off > 0; off >>= 1) {
    if (tid < off) s[tid] += s[tid + off];
    __syncthreads();
  }
  if (tid == 0) bsum[blockIdx.x] = s[0];
}

__global__ void k_s2(int* bsum) {
  __shared__ int s[512];
  int tid = threadIdx.x;
  int v = (tid < NBLK) ? bsum[tid] : 0;
  s[tid] = v;
  __syncthreads();
  for (int off = 1; off < 512; off <<= 1) {
    int t = (tid >= off) ? s[tid - off] : 0;
    __syncthreads();
    s[tid] += t;
    __syncthreads();
  }
  if (tid < NBLK) bsum[tid] = s[tid] - v;
}

__global__ void k_s3(const int* cnt, const int* bsum, int* offsets, int* cursor) {
  __shared__ int s[256];
  int tid = threadIdx.x;
  int i = blockIdx.x * 256 + tid;
  int v = (i < NN) ? cnt[i] : 0;
  s[tid] = v;
  __syncthreads();
  for (int off = 1; off < 256; off <<= 1) {
    int t = (tid >= off) ? s[tid - off] : 0;
    __syncthreads();
    s[tid] += t;
    __syncthreads();
  }
  int o = bsum[blockIdx.x] + s[tid] - v;
  if (i < NN) { offsets[i] = o; cursor[i] = o; }
  if (i == 0) offsets[NN] = NE;
}

__global__ void k_scatter(const int* __restrict__ edges, const int* __restrict__ flag,
                          int* cursor, int* __restrict__ csr_src) {
  int e = blockIdx.x * 256 + threadIdx.x;
  if (e < NE) {
    int f = *flag;
    int d = edge_at(edges, f, NE + e);
    int s = edge_at(edges, f, e);
    int pos = atomicAdd(&cursor[d], 1);
    // atomicExch (vs plain store): RMW executes at L2 and allocates the
    // line, so random 4B writes merge in L2 instead of streaming partial
    // 64B transactions to HBM (was 105 MB WRITE_SIZE for 6.4 MB of data).
    atomicExch(&csr_src[pos], s);
  }
}

// ---------------- Aggregation 1 (+b1): agg1[n] = sum bf16 h1[src] + b1 -----
__global__ __launch_bounds__(256) void k_agg1(const ushort* __restrict__ h1b,
                                              const int* __restrict__ offsets,
                                              const int* __restrict__ csr_src,
                                              const float* __restrict__ b1,
                                              float* __restrict__ agg1) {
  int w = threadIdx.x >> 6, lane = threadIdx.x & 63;
  int n = blockIdx.x * 4 + w;
  if (n >= NN) return;
  int beg = offsets[n], end = offsets[n + 1];
  const uint* h = (const uint*)h1b;  // 2 bf16 per uint
  float2 acc = ((const float2*)b1)[lane];
  int i = beg;
  for (; i + 1 < end; i += 2) {
    uint v0 = h[(size_t)csr_src[i] * 64 + lane];
    uint v1 = h[(size_t)csr_src[i + 1] * 64 + lane];
    acc.x += __uint_as_float(v0 << 16) + __uint_as_float(v1 << 16);
    acc.y += __uint_as_float(v0 & 0xffff0000u) + __uint_as_float(v1 & 0xffff0000u);
  }
  if (i < end) {
    uint v = h[(size_t)csr_src[i] * 64 + lane];
    acc.x += __uint_as_float(v << 16);
    acc.y += __uint_as_float(v & 0xffff0000u);
  }
  ((float2*)agg1)[(size_t)n * 64 + lane] = acc;
}

// ---------------- BN stats -------------------------------------------------
__global__ __launch_bounds__(256) void k_bnstats(const float* __restrict__ agg1,
                                                 float* __restrict__ gsum,
                                                 float* __restrict__ gsq) {
  __shared__ float ss[256], qq[256];
  int tid = threadIdx.x;
  int col = tid & 127, half = tid >> 7;
  int r0 = blockIdx.x * 128;
  float s = 0.f, q = 0.f;
  for (int k = 0; k < 64; ++k) {
    int r = r0 + half + 2 * k;
    if (r < NN) {
      float v = agg1[(size_t)r * HID + col];
      s += v; q += v * v;
    }
  }
  ss[tid] = s; qq[tid] = q;
  __syncthreads();
  if (tid < 128) {
    atomicAdd(&gsum[tid], ss[tid] + ss[tid + 128]);
    atomicAdd(&gsq[tid], qq[tid] + qq[tid + 128]);
  }
}

__global__ void k_bnfin(const float* __restrict__ gsum, const float* __restrict__ gsq,
                        const float* __restrict__ gamma, const float* __restrict__ beta,
                        float* __restrict__ isg, float* __restrict__ bb) {
  int c = threadIdx.x;  // 128 threads
  float mean = gsum[c] * (1.f / NN);
  float var = gsq[c] * (1.f / NN) - mean * mean;
  var = fmaxf(var, 0.f);
  float inv = 1.f / sqrtf(var + BN_EPS);
  float g = gamma[c] * inv;
  isg[c] = g;
  bb[c] = beta[c] - mean * g;
}

// ---------------- GEMM2 (BN+ReLU fused on A): h2b = bf16(relu(bn(agg1))@W2)-
__global__ __launch_bounds__(256) void k_gemm2(const float* __restrict__ agg1,
                                               const float* __restrict__ W2,
                                               const float* __restrict__ isg,
                                               const float* __restrict__ bb,
                                               ushort* __restrict__ h2b) {
  __shared__ float As[32][132];
  __shared__ float Bs[32][68];
  __shared__ float isgS[128], bbS[128];
  const int tid = threadIdx.x;
  if (tid < 128) { isgS[tid] = isg[tid]; bbS[tid] = bb[tid]; }
  __syncthreads();
  const int tr = tid >> 4, tc = tid & 15;
  const int row0 = blockIdx.x * 128;
  float acc[8][4];
#pragma unroll
  for (int i = 0; i < 8; ++i)
#pragma unroll
    for (int j = 0; j < 4; ++j) acc[i][j] = 0.f;

  for (int kt = 0; kt < HID; kt += 32) {
#pragma unroll
    for (int rr = 0; rr < 4; ++rr) {
      int idx = tid + rr * 256;
      int r = idx >> 3;
      int c = (idx & 7) << 2;
      int row = row0 + r; if (row > NN - 1) row = NN - 1;
      float4 v = *(const float4*)(agg1 + (size_t)row * HID + kt + c);
      int k0 = kt + c;
      v.x = fmaxf(fmaf(v.x, isgS[k0 + 0], bbS[k0 + 0]), 0.f);
      v.y = fmaxf(fmaf(v.y, isgS[k0 + 1], bbS[k0 + 1]), 0.f);
      v.z = fmaxf(fmaf(v.z, isgS[k0 + 2], bbS[k0 + 2]), 0.f);
      v.w = fmaxf(fmaf(v.w, isgS[k0 + 3], bbS[k0 + 3]), 0.f);
      As[c + 0][r] = v.x; As[c + 1][r] = v.y;
      As[c + 2][r] = v.z; As[c + 3][r] = v.w;
    }
#pragma unroll
    for (int rr = 0; rr < 2; ++rr) {
      int idx = tid + rr * 256;
      int kk = idx >> 4;
      int cc = (idx & 15) << 2;
      *(float4*)&Bs[kk][cc] = *(const float4*)(W2 + (size_t)(kt + kk) * OUTD + cc);
    }
    __syncthreads();
#pragma unroll
    for (int kk = 0; kk < 32; ++kk) {
      float a[8], b[4];
      *(float4*)&a[0] = *(const float4*)&As[kk][tr * 8];
      *(float4*)&a[4] = *(const float4*)&As[kk][tr * 8 + 4];
      *(float4*)&b[0] = *(const float4*)&Bs[kk][tc * 4];
#pragma unroll
      for (int i = 0; i < 8; ++i)
#pragma unroll
        for (int j = 0; j < 4; ++j) acc[i][j] = fmaf(a[i], b[j], acc[i][j]);
    }
    __syncthreads();
  }
#pragma unroll
  for (int i = 0; i < 8; ++i) {
    int row = row0 + tr * 8 + i;
    if (row < NN) {
      ushort4 o;
      o.x = f2bf_n(acc[i][0]); o.y = f2bf_n(acc[i][1]);
      o.z = f2bf_n(acc[i][2]); o.w = f2bf_n(acc[i][3]);
      *(ushort4*)(h2b + (size_t)row * OUTD + tc * 4) = o;
    }
  }
}

// ---------------- Aggregation 2 + b2 + L2 normalize + fp32 store -----------
__global__ __launch_bounds__(256) void k_agg2norm(const ushort* __restrict__ h2b,
                                                  const int* __restrict__ offsets,
                                                  const int* __restrict__ csr_src,
                                                  const float* __restrict__ b2,
                                                  float* __restrict__ out) {
  int w = threadIdx.x >> 6, lane = threadIdx.x & 63;
  int n = blockIdx.x * 4 + w;
  if (n >= NN) return;
  int beg = offsets[n], end = offsets[n + 1];
  float acc = b2[lane];
  int i = beg;
  for (; i + 1 < end; i += 2) {
    acc += bf2f(h2b[(size_t)csr_src[i] * OUTD + lane]) +
           bf2f(h2b[(size_t)csr_src[i + 1] * OUTD + lane]);
  }
  if (i < end) acc += bf2f(h2b[(size_t)csr_src[i] * OUTD + lane]);
  float q = acc * acc;
#pragma unroll
  for (int off = 32; off > 0; off >>= 1) q += __shfl_xor(q, off);
  float norm = sqrtf(q);
  float scale = 1.f / fmaxf(norm, 1e-12f);
  out[(size_t)n * OUTD + lane] = acc * scale;
}

// ---------------- launch ----------------------------------------------------
extern "C" void kernel_launch(void* const* d_in, const int* in_sizes, int n_in,
                              void* d_out, int out_size, void* d_ws, size_t ws_size,
                              hipStream_t stream) {
  const float* x     = (const float*)d_in[0];
  const int*   edges = (const int*)d_in[1];
  const float* W1    = (const float*)d_in[2];
  const float* b1    = (const float*)d_in[3];
  const float* W2    = (const float*)d_in[4];
  const float* b2    = (const float*)d_in[5];
  const float* gamma = (const float*)d_in[6];
  const float* beta  = (const float*)d_in[7];

  char* ws = (char*)d_ws;
  ushort* h1b    = (ushort*)(ws);                 // 25.6 MB
  float*  agg1   = (float*)(ws + 26000000);       // 51.2 MB
  int*    csr_src= (int*)(ws + 77500000);         // 6.4 MB
  int*    offsets= (int*)(ws + 84000000);         // 100001 ints
  int*    cursor = (int*)(ws + 84400128);         // aliased as cnt during build
  int*    bsum   = (int*)(ws + 84800256);         // 391 ints
  float*  gsum   = (float*)(ws + 84802048);       // 128 f
  float*  gsq    = (float*)(ws + 84802560);       // 128 f
  float*  isg    = (float*)(ws + 84803072);       // 128 f
  float*  bbv    = (float*)(ws + 84803584);       // 128 f
  int*    eflag  = (int*)(ws + 84804096);         // 1 int
  ushort* Wth    = (ushort*)(ws + 84804608);      // 128 KB
  ushort* Wtl    = (ushort*)(ws + 84935680);      // 128 KB
  ushort* h2b    = h1b;                           // reuse (h1b dead after agg1)

  if (ws_size < 85100000) return;  // scratch layout requirement

  hipMemsetAsync(cursor, 0, (NN + 1) * sizeof(int), stream);  // cnt = 0
  hipMemsetAsync(gsum, 0, 1024, stream);                      // gsum+gsq = 0

  k_detect<<<1, 64, 0, stream>>>(edges, eflag);
  k_prepW<<<256, 256, 0, stream>>>(W1, Wth, Wtl);
  k_gemm1m<<<782, 256, 0, stream>>>(x, Wth, Wtl, h1b);
  k_count<<<6250, 256, 0, stream>>>(edges, eflag, cursor);
  k_s1<<<NBLK, 256, 0, stream>>>(cursor, bsum);
  k_s2<<<1, 512, 0, stream>>>(bsum);
  k_s3<<<NBLK, 256, 0, stream>>>(cursor, bsum, offsets, cursor);
  k_scatter<<<6250, 256, 0, stream>>>(edges, eflag, cursor, csr_src);
  k_agg1<<<25000, 256, 0, stream>>>(h1b, offsets, csr_src, b1, agg1);
  k_bnstats<<<782, 256, 0, stream>>>(agg1, gsum, gsq);
  k_bnfin<<<1, 128, 0, stream>>>(gsum, gsq, gamma, beta, isg, bbv);
  k_gemm2<<<782, 256, 0, stream>>>(agg1, W2, isg, bbv, h2b);
  k_agg2norm<<<25000, 256, 0, stream>>>(h2b, offsets, csr_src, b2,
                                        (float*)d_out);
}

// Round 5
// 455.599 us; speedup vs baseline: 1.2746x; 1.2746x over previous
//
#include <hip/hip_runtime.h>
#include <hip/hip_bf16.h>
#include <stdint.h>

#define NN 100000
#define NE 1600000
#define IND 512
#define HID 128
#define OUTD 64
#define BN_EPS 1e-5f
#define NP 98        // ceil(NN/1024) dst partitions
#define PSZ 1024     // nodes per partition
#define PCAP 20480   // staging capacity per partition (mean 16384, +32 sigma)
#define BINCH 8192   // edges per k_bin block

typedef __attribute__((ext_vector_type(8))) short short8v;
typedef __attribute__((ext_vector_type(4))) float f32x4;

// ---- fp32 -> bf16 (RNE) ----------------------------------------------------
__device__ __forceinline__ ushort f2bf(float f, float& back) {
  uint u = __float_as_uint(f);
  uint r = u + 0x7FFFu + ((u >> 16) & 1u);
  ushort h = (ushort)(r >> 16);
  back = __uint_as_float(((uint)h) << 16);
  return h;
}
__device__ __forceinline__ ushort f2bf_n(float f) {
  uint u = __float_as_uint(f);
  uint r = u + 0x7FFFu + ((u >> 16) & 1u);
  return (ushort)(r >> 16);
}
__device__ __forceinline__ float bf2f(ushort h) {
  return __uint_as_float(((uint)h) << 16);
}

// ---------------- edge dtype probe -----------------------------------------
__global__ void k_detect(const int* __restrict__ e, int* __restrict__ flag) {
  __shared__ int nz;
  if (threadIdx.x == 0) nz = 0;
  __syncthreads();
  int v = e[2 * threadIdx.x + 1];
  if (v != 0) atomicAdd(&nz, 1);
  __syncthreads();
  if (threadIdx.x == 0) *flag = (nz == 0) ? 1 : 0;  // 1 => int64
}

__device__ __forceinline__ int edge_at(const int* e32, int f, int i) {
  if (f) return (int)((const long long*)e32)[i];
  return e32[i];
}

// ---------------- W1^T split prep: Wt[n][k] hi/lo bf16 ----------------------
__global__ void k_prepW(const float* __restrict__ W1, ushort* __restrict__ Wth,
                        ushort* __restrict__ Wtl) {
  int i = blockIdx.x * 256 + threadIdx.x;  // over 128*512
  if (i >= HID * IND) return;
  int n = i >> 9, k = i & 511;
  float w = W1[(size_t)k * HID + n];
  float back;
  ushort h = f2bf(w, back);
  Wth[i] = h;
  Wtl[i] = f2bf_n(w - back);
}

// ---------------- GEMM1 via split-bf16 MFMA: h1b = bf16(x @ W1) -------------
__global__ __launch_bounds__(256) void k_gemm1m(const float* __restrict__ x,
                                                const ushort* __restrict__ Wth,
                                                const ushort* __restrict__ Wtl,
                                                ushort* __restrict__ h1b) {
  __shared__ ushort sAh[128 * 40];
  __shared__ ushort sBh[128 * 40], sBl[128 * 40];
  const int tid = threadIdx.x;
  const int lane = tid & 63, wid = tid >> 6;
  const int wr = wid >> 1, wc = wid & 1;
  const int lrow = lane & 15, lkg = lane >> 4;
  const int row0 = blockIdx.x * 128;

  f32x4 acc[4][4];
#pragma unroll
  for (int m = 0; m < 4; ++m)
#pragma unroll
    for (int n = 0; n < 4; ++n) acc[m][n] = (f32x4){0.f, 0.f, 0.f, 0.f};

  float4 ra[4];
  uint4 rbh[2], rbl[2];

#pragma unroll
  for (int i = 0; i < 4; ++i) {
    int flat = i * 256 + tid, r = flat >> 3, kq = flat & 7;
    int grow = row0 + r; if (grow > NN - 1) grow = NN - 1;
    ra[i] = *(const float4*)(x + (size_t)grow * IND + kq * 4);
  }
#pragma unroll
  for (int i = 0; i < 2; ++i) {
    int flat = i * 256 + tid, col = flat >> 2, kc = flat & 3;
    rbh[i] = *(const uint4*)(Wth + (size_t)col * IND + kc * 8);
    rbl[i] = *(const uint4*)(Wtl + (size_t)col * IND + kc * 8);
  }

  for (int s = 0; s < 16; ++s) {
    __syncthreads();
#pragma unroll
    for (int i = 0; i < 4; ++i) {
      int flat = i * 256 + tid, r = flat >> 3, kq = flat & 7;
      ushort4 hi;
      hi.x = f2bf_n(ra[i].x);
      hi.y = f2bf_n(ra[i].y);
      hi.z = f2bf_n(ra[i].z);
      hi.w = f2bf_n(ra[i].w);
      *(ushort4*)&sAh[r * 40 + kq * 4] = hi;
    }
#pragma unroll
    for (int i = 0; i < 2; ++i) {
      int flat = i * 256 + tid, col = flat >> 2, kc = flat & 3;
      *(uint4*)&sBh[col * 40 + kc * 8] = rbh[i];
      *(uint4*)&sBl[col * 40 + kc * 8] = rbl[i];
    }
    if (s < 15) {
      int kt = (s + 1) * 32;
#pragma unroll
      for (int i = 0; i < 4; ++i) {
        int flat = i * 256 + tid, r = flat >> 3, kq = flat & 7;
        int grow = row0 + r; if (grow > NN - 1) grow = NN - 1;
        ra[i] = *(const float4*)(x + (size_t)grow * IND + kt + kq * 4);
      }
#pragma unroll
      for (int i = 0; i < 2; ++i) {
        int flat = i * 256 + tid, col = flat >> 2, kc = flat & 3;
        rbh[i] = *(const uint4*)(Wth + (size_t)col * IND + kt + kc * 8);
        rbl[i] = *(const uint4*)(Wtl + (size_t)col * IND + kt + kc * 8);
      }
    }
    __syncthreads();
    short8v ah[4], bh[4], bl[4];
#pragma unroll
    for (int m = 0; m < 4; ++m) {
      int r = wr * 64 + m * 16 + lrow;
      ah[m] = *(const short8v*)&sAh[r * 40 + lkg * 8];
    }
#pragma unroll
    for (int n = 0; n < 4; ++n) {
      int c = wc * 64 + n * 16 + lrow;
      bh[n] = *(const short8v*)&sBh[c * 40 + lkg * 8];
      bl[n] = *(const short8v*)&sBl[c * 40 + lkg * 8];
    }
#pragma unroll
    for (int m = 0; m < 4; ++m)
#pragma unroll
      for (int n = 0; n < 4; ++n) {
        acc[m][n] = __builtin_amdgcn_mfma_f32_16x16x32_bf16(ah[m], bh[n], acc[m][n], 0, 0, 0);
        acc[m][n] = __builtin_amdgcn_mfma_f32_16x16x32_bf16(ah[m], bl[n], acc[m][n], 0, 0, 0);
      }
  }

#pragma unroll
  for (int m = 0; m < 4; ++m) {
    int orow0 = row0 + wr * 64 + m * 16 + (lane >> 4) * 4;
#pragma unroll
    for (int i = 0; i < 4; ++i) {
      int grow = orow0 + i;
      if (grow < NN) {
#pragma unroll
        for (int n = 0; n < 4; ++n) {
          h1b[(size_t)grow * HID + wc * 64 + n * 16 + (lane & 15)] = f2bf_n(acc[m][n][i]);
        }
      }
    }
  }
}

// ---------------- CSR build pass 1: partition binning -----------------------
// Each block: LDS-sort its 8192-edge chunk by dst partition, reserve one
// contiguous run per partition (1 atomicAdd), flush runs coalesced.
__global__ __launch_bounds__(256) void k_bin(const int* __restrict__ edges,
                                             const int* __restrict__ flag,
                                             int* __restrict__ gCursor,
                                             int* __restrict__ staging) {
  __shared__ int cnt[NP], scn[NP], base[NP], cur[NP];
  __shared__ int items[BINCH];  // 32 KB
  const int tid = threadIdx.x;
  const int e0 = blockIdx.x * BINCH;
  const int ecnt = min(BINCH, NE - e0);
  const int f = *flag;
  for (int i = tid; i < NP; i += 256) cnt[i] = 0;
  __syncthreads();
  for (int i = tid; i < ecnt; i += 256) {
    int d = edge_at(edges, f, NE + e0 + i);
    atomicAdd(&cnt[d >> 10], 1);
  }
  __syncthreads();
  if (tid == 0) {
    int s = 0;
    for (int p = 0; p < NP; ++p) { scn[p] = s; s += cnt[p]; }
  }
  __syncthreads();
  if (tid < NP) {
    base[tid] = (cnt[tid] > 0) ? atomicAdd(&gCursor[tid], cnt[tid]) : 0;
    cur[tid] = 0;
  }
  __syncthreads();
  for (int i = tid; i < ecnt; i += 256) {
    int d = edge_at(edges, f, NE + e0 + i);
    int s = edge_at(edges, f, e0 + i);
    int p = d >> 10;
    int lp = atomicAdd(&cur[p], 1);
    items[scn[p] + lp] = (s << 10) | (d & (PSZ - 1));
  }
  __syncthreads();
  for (int p = 0; p < NP; ++p) {
    int c = cnt[p];
    if (c == 0) continue;
    int gb = base[p];
    int* dst = staging + (size_t)p * PCAP;
    for (int i = tid; i < c; i += 256) {
      int gpos = gb + i;
      if (gpos < PCAP) dst[gpos] = items[scn[p] + i];
    }
  }
}

// ---------------- CSR build pass 2a: scan partition totals ------------------
__global__ void k_partscan(const int* __restrict__ gCursor,
                           int* __restrict__ partBase, int* __restrict__ offsets) {
  __shared__ int s[128];
  int tid = threadIdx.x;
  int v = (tid < NP) ? min(gCursor[tid], PCAP) : 0;
  s[tid] = v;
  __syncthreads();
  for (int off = 1; off < 128; off <<= 1) {
    int t = (tid >= off) ? s[tid - off] : 0;
    __syncthreads();
    s[tid] += t;
    __syncthreads();
  }
  if (tid < NP) partBase[tid] = s[tid] - v;
  if (tid == 0) { partBase[NP] = NE; offsets[NN] = NE; }
}

// ---------------- CSR build pass 2b: per-partition counting sort ------------
__global__ __launch_bounds__(256) void k_csrpart(const int* __restrict__ staging,
                                                 const int* __restrict__ gCursor,
                                                 const int* __restrict__ partBase,
                                                 int* __restrict__ offsets,
                                                 int* __restrict__ csr_src) {
  __shared__ int cnt[PSZ];       // becomes exclusive scan
  __shared__ int cur[PSZ];
  __shared__ int tsum[256];
  __shared__ int srcbuf[PCAP];   // 80 KB
  const int tid = threadIdx.x;
  const int p = blockIdx.x;
  const int tot = min(gCursor[p], PCAP);
  const int gbase = partBase[p];
  const int* st = staging + (size_t)p * PCAP;
  for (int i = tid; i < PSZ; i += 256) { cnt[i] = 0; cur[i] = 0; }
  __syncthreads();
  for (int i = tid; i < tot; i += 256) atomicAdd(&cnt[st[i] & (PSZ - 1)], 1);
  __syncthreads();
  // exclusive scan of 1024 counters: 4 per thread + 256-wide scan
  int b0 = tid * 4;
  int c0 = cnt[b0], c1 = cnt[b0 + 1], c2 = cnt[b0 + 2], c3 = cnt[b0 + 3];
  int ls = c0 + c1 + c2 + c3;
  tsum[tid] = ls;
  __syncthreads();
  for (int off = 1; off < 256; off <<= 1) {
    int t = (tid >= off) ? tsum[tid - off] : 0;
    __syncthreads();
    tsum[tid] += t;
    __syncthreads();
  }
  int ebase = tsum[tid] - ls;
  cnt[b0] = ebase;
  cnt[b0 + 1] = ebase + c0;
  cnt[b0 + 2] = ebase + c0 + c1;
  cnt[b0 + 3] = ebase + c0 + c1 + c2;
  __syncthreads();
  for (int i = tid; i < PSZ; i += 256) {
    int node = p * PSZ + i;
    if (node < NN) offsets[node] = gbase + cnt[i];
  }
  for (int i = tid; i < tot; i += 256) {
    int item = st[i];
    int dl = item & (PSZ - 1);
    int lp = atomicAdd(&cur[dl], 1);
    srcbuf[cnt[dl] + lp] = item >> 10;
  }
  __syncthreads();
  for (int i = tid; i < tot; i += 256) csr_src[gbase + i] = srcbuf[i];
}

// ---------------- Aggregation 1 (+b1): agg1[n] = sum bf16 h1[src] + b1 -----
__global__ __launch_bounds__(256) void k_agg1(const ushort* __restrict__ h1b,
                                              const int* __restrict__ offsets,
                                              const int* __restrict__ csr_src,
                                              const float* __restrict__ b1,
                                              float* __restrict__ agg1) {
  int w = threadIdx.x >> 6, lane = threadIdx.x & 63;
  int n = blockIdx.x * 4 + w;
  if (n >= NN) return;
  int beg = offsets[n], end = offsets[n + 1];
  const uint* h = (const uint*)h1b;
  float2 acc = ((const float2*)b1)[lane];
  int i = beg;
  for (; i + 1 < end; i += 2) {
    uint v0 = h[(size_t)csr_src[i] * 64 + lane];
    uint v1 = h[(size_t)csr_src[i + 1] * 64 + lane];
    acc.x += __uint_as_float(v0 << 16) + __uint_as_float(v1 << 16);
    acc.y += __uint_as_float(v0 & 0xffff0000u) + __uint_as_float(v1 & 0xffff0000u);
  }
  if (i < end) {
    uint v = h[(size_t)csr_src[i] * 64 + lane];
    acc.x += __uint_as_float(v << 16);
    acc.y += __uint_as_float(v & 0xffff0000u);
  }
  ((float2*)agg1)[(size_t)n * 64 + lane] = acc;
}

// ---------------- BN stats -------------------------------------------------
__global__ __launch_bounds__(256) void k_bnstats(const float* __restrict__ agg1,
                                                 float* __restrict__ gsum,
                                                 float* __restrict__ gsq) {
  __shared__ float ss[256], qq[256];
  int tid = threadIdx.x;
  int col = tid & 127, half = tid >> 7;
  int r0 = blockIdx.x * 128;
  float s = 0.f, q = 0.f;
  for (int k = 0; k < 64; ++k) {
    int r = r0 + half + 2 * k;
    if (r < NN) {
      float v = agg1[(size_t)r * HID + col];
      s += v; q += v * v;
    }
  }
  ss[tid] = s; qq[tid] = q;
  __syncthreads();
  if (tid < 128) {
    atomicAdd(&gsum[tid], ss[tid] + ss[tid + 128]);
    atomicAdd(&gsq[tid], qq[tid] + qq[tid + 128]);
  }
}

__global__ void k_bnfin(const float* __restrict__ gsum, const float* __restrict__ gsq,
                        const float* __restrict__ gamma, const float* __restrict__ beta,
                        float* __restrict__ isg, float* __restrict__ bb) {
  int c = threadIdx.x;  // 128 threads
  float mean = gsum[c] * (1.f / NN);
  float var = gsq[c] * (1.f / NN) - mean * mean;
  var = fmaxf(var, 0.f);
  float inv = 1.f / sqrtf(var + BN_EPS);
  float g = gamma[c] * inv;
  isg[c] = g;
  bb[c] = beta[c] - mean * g;
}

// ---------------- GEMM2 (BN+ReLU fused on A): h2b = bf16(relu(bn(agg1))@W2)-
__global__ __launch_bounds__(256) void k_gemm2(const float* __restrict__ agg1,
                                               const float* __restrict__ W2,
                                               const float* __restrict__ isg,
                                               const float* __restrict__ bb,
                                               ushort* __restrict__ h2b) {
  __shared__ float As[32][132];
  __shared__ float Bs[32][68];
  __shared__ float isgS[128], bbS[128];
  const int tid = threadIdx.x;
  if (tid < 128) { isgS[tid] = isg[tid]; bbS[tid] = bb[tid]; }
  __syncthreads();
  const int tr = tid >> 4, tc = tid & 15;
  const int row0 = blockIdx.x * 128;
  float acc[8][4];
#pragma unroll
  for (int i = 0; i < 8; ++i)
#pragma unroll
    for (int j = 0; j < 4; ++j) acc[i][j] = 0.f;

  for (int kt = 0; kt < HID; kt += 32) {
#pragma unroll
    for (int rr = 0; rr < 4; ++rr) {
      int idx = tid + rr * 256;
      int r = idx >> 3;
      int c = (idx & 7) << 2;
      int row = row0 + r; if (row > NN - 1) row = NN - 1;
      float4 v = *(const float4*)(agg1 + (size_t)row * HID + kt + c);
      int k0 = kt + c;
      v.x = fmaxf(fmaf(v.x, isgS[k0 + 0], bbS[k0 + 0]), 0.f);
      v.y = fmaxf(fmaf(v.y, isgS[k0 + 1], bbS[k0 + 1]), 0.f);
      v.z = fmaxf(fmaf(v.z, isgS[k0 + 2], bbS[k0 + 2]), 0.f);
      v.w = fmaxf(fmaf(v.w, isgS[k0 + 3], bbS[k0 + 3]), 0.f);
      As[c + 0][r] = v.x; As[c + 1][r] = v.y;
      As[c + 2][r] = v.z; As[c + 3][r] = v.w;
    }
#pragma unroll
    for (int rr = 0; rr < 2; ++rr) {
      int idx = tid + rr * 256;
      int kk = idx >> 4;
      int cc = (idx & 15) << 2;
      *(float4*)&Bs[kk][cc] = *(const float4*)(W2 + (size_t)(kt + kk) * OUTD + cc);
    }
    __syncthreads();
#pragma unroll
    for (int kk = 0; kk < 32; ++kk) {
      float a[8], b[4];
      *(float4*)&a[0] = *(const float4*)&As[kk][tr * 8];
      *(float4*)&a[4] = *(const float4*)&As[kk][tr * 8 + 4];
      *(float4*)&b[0] = *(const float4*)&Bs[kk][tc * 4];
#pragma unroll
      for (int i = 0; i < 8; ++i)
#pragma unroll
        for (int j = 0; j < 4; ++j) acc[i][j] = fmaf(a[i], b[j], acc[i][j]);
    }
    __syncthreads();
  }
#pragma unroll
  for (int i = 0; i < 8; ++i) {
    int row = row0 + tr * 8 + i;
    if (row < NN) {
      ushort4 o;
      o.x = f2bf_n(acc[i][0]); o.y = f2bf_n(acc[i][1]);
      o.z = f2bf_n(acc[i][2]); o.w = f2bf_n(acc[i][3]);
      *(ushort4*)(h2b + (size_t)row * OUTD + tc * 4) = o;
    }
  }
}

// ---------------- Aggregation 2 + b2 + L2 normalize + fp32 store -----------
__global__ __launch_bounds__(256) void k_agg2norm(const ushort* __restrict__ h2b,
                                                  const int* __restrict__ offsets,
                                                  const int* __restrict__ csr_src,
                                                  const float* __restrict__ b2,
                                                  float* __restrict__ out) {
  int w = threadIdx.x >> 6, lane = threadIdx.x & 63;
  int n = blockIdx.x * 4 + w;
  if (n >= NN) return;
  int beg = offsets[n], end = offsets[n + 1];
  float acc = b2[lane];
  int i = beg;
  for (; i + 1 < end; i += 2) {
    acc += bf2f(h2b[(size_t)csr_src[i] * OUTD + lane]) +
           bf2f(h2b[(size_t)csr_src[i + 1] * OUTD + lane]);
  }
  if (i < end) acc += bf2f(h2b[(size_t)csr_src[i] * OUTD + lane]);
  float q = acc * acc;
#pragma unroll
  for (int off = 32; off > 0; off >>= 1) q += __shfl_xor(q, off);
  float norm = sqrtf(q);
  float scale = 1.f / fmaxf(norm, 1e-12f);
  out[(size_t)n * OUTD + lane] = acc * scale;
}

// ---------------- launch ----------------------------------------------------
extern "C" void kernel_launch(void* const* d_in, const int* in_sizes, int n_in,
                              void* d_out, int out_size, void* d_ws, size_t ws_size,
                              hipStream_t stream) {
  const float* x     = (const float*)d_in[0];
  const int*   edges = (const int*)d_in[1];
  const float* W1    = (const float*)d_in[2];
  const float* b1    = (const float*)d_in[3];
  const float* W2    = (const float*)d_in[4];
  const float* b2    = (const float*)d_in[5];
  const float* gamma = (const float*)d_in[6];
  const float* beta  = (const float*)d_in[7];

  char* ws = (char*)d_ws;
  ushort* h1b     = (ushort*)(ws);                // 25.6 MB
  float*  agg1    = (float*)(ws + 26000000);      // 51.2 MB
  int*    csr_src = (int*)(ws + 77500000);        // 6.4 MB
  int*    offsets = (int*)(ws + 84000000);        // 100001 ints
  int*    staging = (int*)(ws + 84400128);        // 98*20480*4 = 8,028,160 B
  int*    gCursor = (int*)(ws + 92428544);        // 98 ints (512B region)
  int*    partBase= (int*)(ws + 92429056);        // 99 ints (512B region)
  float*  gsum    = (float*)(ws + 92429568);      // 128 f
  float*  gsq     = (float*)(ws + 92430080);      // 128 f
  float*  isg     = (float*)(ws + 92430592);      // 128 f
  float*  bbv     = (float*)(ws + 92431104);      // 128 f
  int*    eflag   = (int*)(ws + 92431616);        // 1 int
  ushort* Wth     = (ushort*)(ws + 92432128);     // 128 KB
  ushort* Wtl     = (ushort*)(ws + 92563200);     // 128 KB
  ushort* h2b     = h1b;                          // reuse (h1b dead after agg1)

  if (ws_size < 92700000) return;  // scratch layout requirement

  // zero gCursor + partBase + gsum + gsq (2 KB)
  hipMemsetAsync(gCursor, 0, 2048, stream);

  k_detect<<<1, 64, 0, stream>>>(edges, eflag);
  k_prepW<<<256, 256, 0, stream>>>(W1, Wth, Wtl);
  k_gemm1m<<<782, 256, 0, stream>>>(x, Wth, Wtl, h1b);
  k_bin<<<196, 256, 0, stream>>>(edges, eflag, gCursor, staging);
  k_partscan<<<1, 128, 0, stream>>>(gCursor, partBase, offsets);
  k_csrpart<<<NP, 256, 0, stream>>>(staging, gCursor, partBase, offsets, csr_src);
  k_agg1<<<25000, 256, 0, stream>>>(h1b, offsets, csr_src, b1, agg1);
  k_bnstats<<<782, 256, 0, stream>>>(agg1, gsum, gsq);
  k_bnfin<<<1, 128, 0, stream>>>(gsum, gsq, gamma, beta, isg, bbv);
  k_gemm2<<<782, 256, 0, stream>>>(agg1, W2, isg, bbv, h2b);
  k_agg2norm<<<25000, 256, 0, stream>>>(h2b, offsets, csr_src, b2,
                                        (float*)d_out);
}